// Round 1
// baseline (116.851 us; speedup 1.0000x reference)
//
#include <hip/hip_runtime.h>
#include <hip/hip_bf16.h>

// LengthRegulator: x (B=32, C=384, T=1024) f32, duration (B, T) i32 in [0,8),
// max_len = 7168. out0 = x gathered along T by frame->token map, zeroed past
// mel_len; out1 = mel_len (written as f32 values, harness reads flat f32).

#define B_ 32
#define C_ 384
#define T_ 1024
#define MAXLEN_ 7168

// ---------------- Kernel A: scan + scatter index map + mel_len ----------------
__global__ __launch_bounds__(1024) void lr_scan_kernel(
    const int* __restrict__ dur,   // (B, T)
    int* __restrict__ idx,         // (B, MAXLEN) workspace
    float* __restrict__ mel_out)   // (B,) tail of d_out, stored as float
{
    const int b = blockIdx.x;
    const int t = threadIdx.x;            // blockDim.x == T_ == 1024
    __shared__ int s[T_];

    const int v = dur[b * T_ + t];
    s[t] = v;
    __syncthreads();

    // Hillis-Steele inclusive scan over 1024 elements (10 steps)
    #pragma unroll
    for (int off = 1; off < T_; off <<= 1) {
        int add = (t >= off) ? s[t - off] : 0;
        __syncthreads();
        s[t] += add;
        __syncthreads();
    }

    const int csum = s[t];          // inclusive
    const int start = csum - v;     // exclusive
    const int mel = s[T_ - 1];      // total frames for this batch (<= 7168)

    int* irow = idx + (size_t)b * MAXLEN_;

    // token t owns frames [start, start+v)
    for (int k = 0; k < v; ++k)
        irow[start + k] = t;

    // invalid frames -> -1 (output zero)
    for (int f = mel + t; f < MAXLEN_; f += T_)
        irow[f] = -1;

    if (t == 0)
        mel_out[b] = (float)mel;
}

// ---------------- Kernel B: broadcast gather, one block per (b,c) row --------
__global__ __launch_bounds__(256) void lr_gather_kernel(
    const float* __restrict__ x,   // (B, C, T)
    const int* __restrict__ idx,   // (B, MAXLEN)
    float* __restrict__ out)       // (B, C, MAXLEN)
{
    const int bc = blockIdx.x;
    const int b = bc / C_;
    const int c = bc - b * C_;

    const float* __restrict__ xr = x + ((size_t)b * C_ + c) * T_;   // 4 KB row
    const int4*  __restrict__ ir = (const int4*)(idx + (size_t)b * MAXLEN_);
    float4* __restrict__ orow = (float4*)(out + ((size_t)b * C_ + c) * MAXLEN_);

    const int n4 = MAXLEN_ / 4;    // 1792
    for (int i = threadIdx.x; i < n4; i += 256) {
        const int4 id = ir[i];
        float4 v;
        v.x = (id.x >= 0) ? xr[id.x] : 0.0f;
        v.y = (id.y >= 0) ? xr[id.y] : 0.0f;
        v.z = (id.z >= 0) ? xr[id.z] : 0.0f;
        v.w = (id.w >= 0) ? xr[id.w] : 0.0f;
        orow[i] = v;
    }
}

extern "C" void kernel_launch(void* const* d_in, const int* in_sizes, int n_in,
                              void* d_out, int out_size, void* d_ws, size_t ws_size,
                              hipStream_t stream) {
    const float* x   = (const float*)d_in[0];
    const int*   dur = (const int*)d_in[1];
    // d_in[2] = max_len scalar (7168), compile-time constant here.

    float* out = (float*)d_out;
    float* mel_out = out + (size_t)B_ * C_ * MAXLEN_;   // 32 floats at the tail
    int* idx = (int*)d_ws;                               // 32*7168*4 = 896 KiB

    lr_scan_kernel<<<B_, 1024, 0, stream>>>(dur, idx, mel_out);
    lr_gather_kernel<<<B_ * C_, 256, 0, stream>>>(x, idx, out);
}

// Round 3
// 72.850 us; speedup vs baseline: 1.6040x; 1.6040x over previous
//
#include <hip/hip_runtime.h>

// LengthRegulator fused: x (B=32, C=384, T=1024) f32, duration (B,T) i32 in [0,8),
// max_len = 7168. One kernel: each block = (batch b, 1024-frame tile, 8 channels).
// Block re-computes duration scan (cheap, 4KB + shuffle scan), scatters its
// tile's frame->token map into LDS, then gathers 8 channels with token ids in
// registers. out0 = gathered x (zero past mel_len); out1 = mel_len as f32.

#define B_ 32
#define C_ 384
#define T_ 1024
#define MAXLEN_ 7168
#define FT_ 7          // frame tiles of 1024 (7*1024 = 7168)
#define CPB_ 8         // channels per block
#define NT_ 256        // threads per block

typedef float f32x4 __attribute__((ext_vector_type(4)));

__global__ __launch_bounds__(NT_) void lr_fused_kernel(
    const int* __restrict__ dur,     // (B, T)
    const float* __restrict__ x,     // (B, C, T)
    float* __restrict__ out,         // (B, C, MAXLEN)
    float* __restrict__ mel_out)     // (B,) stored as float
{
    const int tid   = threadIdx.x;
    const int ftile = blockIdx.x;    // 0..FT_-1
    const int cblk  = blockIdx.y;    // 0..C_/CPB_-1
    const int b     = blockIdx.z;    // 0..B_-1
    const int f0    = ftile << 10;   // tile start frame

    __shared__ int s_tok[1024];      // frame->token map for this tile
    __shared__ int s_w[NT_ / 64];    // per-wave scan totals

    // ---- each thread loads 4 consecutive durations (coalesced int4) ----
    const int4 d4 = ((const int4*)(dur + b * T_))[tid];
    const int sum4 = d4.x + d4.y + d4.z + d4.w;

    // ---- inclusive scan of per-thread sums: wave shuffle + LDS cross-wave ----
    const int lane = tid & 63;
    const int wave = tid >> 6;
    int sc = sum4;
    #pragma unroll
    for (int d = 1; d < 64; d <<= 1) {
        int n = __shfl_up(sc, d, 64);
        if (lane >= d) sc += n;
    }
    if (lane == 63) s_w[wave] = sc;

    // init frame->token map to -1 (frames past mel_len stay -1 -> zero output)
    ((int4*)s_tok)[tid] = make_int4(-1, -1, -1, -1);
    __syncthreads();

    int woff = 0;
    #pragma unroll
    for (int w = 0; w < NT_ / 64; ++w)
        woff += (w < wave) ? s_w[w] : 0;
    const int mel = s_w[0] + s_w[1] + s_w[2] + s_w[3];

    // exclusive start frame of this thread's first token
    const int st = woff + sc - sum4;

    // ---- scatter: token k covers frames [start_k, start_k + dur_k) ----
    {
        const int base_tok = tid << 2;
        const int s0 = st;
        const int s1 = s0 + d4.x;
        const int s2 = s1 + d4.y;
        const int s3 = s2 + d4.z;
        const int starts[4] = { s0, s1, s2, s3 };
        const int lens[4]   = { d4.x, d4.y, d4.z, d4.w };
        #pragma unroll
        for (int k = 0; k < 4; ++k) {
            int lo = starts[k] - f0;
            int hi = lo + lens[k];
            lo = lo < 0 ? 0 : lo;
            hi = hi > 1024 ? 1024 : hi;
            for (int p = lo; p < hi; ++p)
                s_tok[p] = base_tok + k;
        }
    }
    __syncthreads();

    // ---- gather 8 channels; token ids for this thread's 4 frames in regs ----
    const int4 t4 = ((const int4*)s_tok)[tid];

    const float* xb = x + ((size_t)b * C_ + cblk * CPB_) * T_;
    float* ob = out + ((size_t)b * C_ + cblk * CPB_) * MAXLEN_ + f0 + (tid << 2);

    #pragma unroll
    for (int cc = 0; cc < CPB_; ++cc) {
        const float* __restrict__ xr = xb + cc * T_;   // 4 KB row, L1-resident
        f32x4 v;
        v.x = (t4.x >= 0) ? xr[t4.x] : 0.0f;
        v.y = (t4.y >= 0) ? xr[t4.y] : 0.0f;
        v.z = (t4.z >= 0) ? xr[t4.z] : 0.0f;
        v.w = (t4.w >= 0) ? xr[t4.w] : 0.0f;
        __builtin_nontemporal_store(v, (f32x4*)(ob + (size_t)cc * MAXLEN_));
    }

    if (ftile == 0 && cblk == 0 && tid == 0)
        mel_out[b] = (float)mel;
}

extern "C" void kernel_launch(void* const* d_in, const int* in_sizes, int n_in,
                              void* d_out, int out_size, void* d_ws, size_t ws_size,
                              hipStream_t stream) {
    const float* x   = (const float*)d_in[0];
    const int*   dur = (const int*)d_in[1];
    // d_in[2] = max_len scalar (7168), compile-time constant here.

    float* out = (float*)d_out;
    float* mel_out = out + (size_t)B_ * C_ * MAXLEN_;  // 32 floats at the tail

    dim3 grid(FT_, C_ / CPB_, B_);
    lr_fused_kernel<<<grid, NT_, 0, stream>>>(dur, x, out, mel_out);
}